// Round 8
// baseline (703.988 us; speedup 1.0000x reference)
//
#include <hip/hip_runtime.h>

#define LOOKBACK 48
#define HORIZON  12
#define TTOT     60
#define INPUT_DIM 8
#define HIDDEN   128
#define GATES    512
#define BATCH    8192
#define TILE_B   16          /* batch rows per block (1 M-tile of 16) */
#define NTHREADS 512         /* 8 waves; wave s owns hidden units s*16..s*16+15 */
#define NSLICES  8
#define L0_KS    5           /* layer0 K = 160 (8 x + 128 h0 + 24 zero-pad) */
#define L1_KS    8           /* layer1 K = 256 (128 h0 + 128 h1) */
#define FRAGS_PER_KS 4       /* 4 gate-type N-tiles, SINGLE fp16 B (no hi/lo) */
#define FRAG_SHORTS 512      /* 1KB per fragment */
#define KSTRIDE  (FRAGS_PER_KS * FRAG_SHORTS)            /* 2048 halves per K-step */
#define SLICE_FRAGS ((L0_KS + L1_KS) * FRAGS_PER_KS)     /* 52 */
#define W_HALFS  (NSLICES * SLICE_FRAGS * FRAG_SHORTS)   /* 212992 halves = 416KB */

/* A-plane LDS (in-place state), fp16 hi+lo planes, 16-row M-tile:
   A0: chunk0 = x (k=0..7), chunks 1..16 = h0 (chunk 1+(u>>3)), 17..19 zero pad.
   A1: chunks 0..15 = h1.
   chunk = [ROWP rows][8 fp16], ROWP=17 (16 rows + 1 pad row). */
#define ROWP 17
#define A0_CHUNKS 20
#define A1_CHUNKS 16
#define A0_HALFS (A0_CHUNKS * ROWP * 8)   /* 2720 */
#define A1_HALFS (A1_CHUNKS * ROWP * 8)   /* 2176 */

typedef __attribute__((ext_vector_type(8))) _Float16 half8;
typedef __attribute__((ext_vector_type(4))) float f32x4;

__device__ __forceinline__ float sigm(float x) {
    return 1.0f / (1.0f + __expf(-x));
}
__device__ __forceinline__ float tanh_fast(float x) {
    float ax = fabsf(x);
    float e  = __expf(-2.0f * ax);
    float t  = (1.0f - e) / (1.0f + e);
    return copysignf(t, x);
}

/* Barrier WITHOUT vmcnt drain: LDS ordering only; global conveyor loads stay
   in flight across the barrier. */
#define BARRIER() __asm__ volatile("s_waitcnt lgkmcnt(0)\ns_barrier" ::: "memory")

// ------------- setup: fp16 weights in MFMA-fragment order -------------
// frag element (lane, j) = W_l[k = ks*32 + (lane>>4)*8 + j][row = t*128 + s*16 + (lane&15)]
__global__ void setup_kernel(const float* __restrict__ Wih0, const float* __restrict__ Whh0,
                             const float* __restrict__ bi0,  const float* __restrict__ bh0,
                             const float* __restrict__ Wih1, const float* __restrict__ Whh1,
                             const float* __restrict__ bi1,  const float* __restrict__ bh1,
                             _Float16* __restrict__ wfrag, float* __restrict__ bias) {
    int idx = blockIdx.x * blockDim.x + threadIdx.x;
    if (idx < W_HALFS) {
        int e = idx & 511, frag = idx >> 9;
        int lane = e >> 3, j = e & 7;
        int t = frag & 3;
        int rest = frag >> 2;
        int lks = rest % (L0_KS + L1_KS), s = rest / (L0_KS + L1_KS);
        int l = (lks < L0_KS) ? 0 : 1;
        int ks = l ? (lks - L0_KS) : lks;
        int k = ks * 32 + ((lane >> 4) << 3) + j;
        int uu = s * 16 + (lane & 15);
        int row = t * HIDDEN + uu;
        float v = 0.0f;
        if (l == 0) {
            if (k < INPUT_DIM) v = Wih0[row * INPUT_DIM + k];
            else if (k < INPUT_DIM + HIDDEN) v = Whh0[row * HIDDEN + (k - INPUT_DIM)];
        } else {
            if (k < HIDDEN) v = Wih1[row * HIDDEN + k];
            else v = Whh1[row * HIDDEN + (k - HIDDEN)];
        }
        wfrag[idx] = (_Float16)v;
    } else if (idx < W_HALFS + 2 * GATES) {
        int g = idx - W_HALFS;
        bias[g] = (g < GATES) ? (bi0[g] + bh0[g]) : (bi1[g - GATES] + bh1[g - GATES]);
    }
}

// ------------- persistent 2-layer LSTM, fp16 MFMA + conveyor, 2 blocks/CU -------------
__global__ __launch_bounds__(NTHREADS, 2)
void lstm_kernel(const float* __restrict__ input,   // [B,60,8]
                 const _Float16* __restrict__ wfrag,
                 const float* __restrict__ bias01,  // [1024]
                 const float* __restrict__ W_fc,    // [128]
                 const float* __restrict__ b_fc,
                 float* __restrict__ out) {         // [B,12]
    __shared__ _Float16 A0h[A0_HALFS], A0l[A0_HALFS];
    __shared__ _Float16 A1h_[A1_HALFS], A1l_[A1_HALFS];
    __shared__ float wfcs[HIDDEN];

    const int tid  = threadIdx.x;
    const int lane = tid & 63;
    const int s    = tid >> 6;
    const int col  = lane & 15;
    const int quad = lane >> 4;
    const int u    = s * 16 + col;
    const int batch0 = blockIdx.x * TILE_B;

    const _Float16* w0 = wfrag + s * (SLICE_FRAGS * FRAG_SHORTS);
    const _Float16* w1 = w0 + L0_KS * KSTRIDE;

    for (int i = tid; i < A0_HALFS; i += NTHREADS) { A0h[i] = (_Float16)0.f; A0l[i] = (_Float16)0.f; }
    for (int i = tid; i < A1_HALFS; i += NTHREADS) { A1h_[i] = (_Float16)0.f; A1l_[i] = (_Float16)0.f; }
    if (tid < HIDDEN) wfcs[tid] = W_fc[tid];
    const float bfc = b_fc[0];

    float bv0[4], bv1[4];
#pragma unroll
    for (int tt = 0; tt < 4; ++tt) {
        bv0[tt] = bias01[tt * HIDDEN + u];
        bv1[tt] = bias01[GATES + tt * HIDDEN + u];
    }

    float c0[4] = {}, c1[4] = {};

    // x(0) prefetch + stage
    float xv = 0.0f;
    if (tid < TILE_B * INPUT_DIM)
        xv = input[(size_t)(batch0 + (tid >> 3)) * (TTOT * INPUT_DIM) + (tid & 7)];
    BARRIER();                               // zero-init visible
    if (tid < TILE_B * INPUT_DIM) {
        int r = tid >> 3, k = tid & 7;
        _Float16 hi = (_Float16)xv;
        A0h[r * 8 + k] = hi;
        A0l[r * 8 + k] = (_Float16)(xv - (float)hi);
    }

    half8 bq[3][4];                          // B conveyor (depth 3, 4 gate frags)
    half8 ah[2], al[2];                      // A hi/lo double buffer (1 M-tile)

#define WPOS(p) ((p) < L0_KS ? (w0 + (p) * KSTRIDE) : (w1 + ((p) - L0_KS) * KSTRIDE))
#define LOADB(p, sl) { const _Float16* wp_ = WPOS(p) + lane * 8;                \
    _Pragma("unroll") for (int tt = 0; tt < 4; ++tt)                            \
        bq[sl][tt] = *(const half8*)(wp_ + tt * FRAG_SHORTS); }
#define LOADA(Hh, Hl, chunk, buf) { int base_ = ((chunk) * ROWP + col) * 8;     \
    ah[buf] = *(const half8*)(Hh + base_);                                      \
    al[buf] = *(const half8*)(Hl + base_); }
#define COMP(ACC, ab, sl)                                                       \
    _Pragma("unroll") for (int tt = 0; tt < 4; ++tt)                            \
        ACC[tt] = __builtin_amdgcn_mfma_f32_16x16x32_f16(                       \
            ah[ab], bq[sl][tt], ACC[tt], 0, 0, 0);                              \
    _Pragma("unroll") for (int tt = 0; tt < 4; ++tt)                            \
        ACC[tt] = __builtin_amdgcn_mfma_f32_16x16x32_f16(                       \
            al[ab], bq[sl][tt], ACC[tt], 0, 0, 0);

    LOADB(0, 0) LOADB(1, 1) LOADB(2, 2)      // prime conveyor
    BARRIER();                               // x(0) staged & visible

#pragma unroll 1
    for (int t = 0; t < TTOT; ++t) {
        // prefetch x(t+1) into registers (consumed after B2)
        if (tid < TILE_B * INPUT_DIM && t + 1 < TTOT)
            xv = input[(size_t)(batch0 + (tid >> 3)) * (TTOT * INPUT_DIM)
                       + (t + 1) * INPUT_DIM + (tid & 7)];

        // ---- layer 0 GEMM: stream pos 0..4 ----
        f32x4 acc[4];
#pragma unroll
        for (int tt = 0; tt < 4; ++tt) {
            f32x4 b = {bv0[tt], bv0[tt], bv0[tt], bv0[tt]};
            acc[tt] = b;
        }
        LOADA(A0h, A0l, quad, 0)
        LOADA(A0h, A0l, 4 + quad, 1)  COMP(acc, 0, 0) LOADB(3, 0)
        LOADA(A0h, A0l, 8 + quad, 0)  COMP(acc, 1, 1) LOADB(4, 1)
        LOADA(A0h, A0l, 12 + quad, 1) COMP(acc, 0, 2) LOADB(5, 2)
        LOADA(A0h, A0l, 16 + quad, 0) COMP(acc, 1, 0) LOADB(6, 0)
                                      COMP(acc, 0, 1) LOADB(7, 1)
        BARRIER();                           // B2: all A0 reads done

        // ---- cell 0 -> write h0 (A0 chunks 1..16); stage x(t+1) chunk 0 ----
#pragma unroll
        for (int r = 0; r < 4; ++r) {
            float ig = sigm(acc[0][r]);
            float fg = sigm(acc[1][r]);
            float gg = tanh_fast(acc[2][r]);
            float og = sigm(acc[3][r]);
            float cn = fg * c0[r] + ig * gg;
            c0[r] = cn;
            float h = og * tanh_fast(cn);
            _Float16 hi = (_Float16)h;
            int row = quad * 4 + r;
            int i0 = ((1 + (u >> 3)) * ROWP + row) * 8 + (u & 7);
            A0h[i0] = hi;
            A0l[i0] = (_Float16)(h - (float)hi);
        }
        if (tid < TILE_B * INPUT_DIM && t + 1 < TTOT) {
            int r = tid >> 3, k = tid & 7;
            if (!(t + 1 > LOOKBACK && k == 0)) {   // BG slot filled by fc instead
                _Float16 hi = (_Float16)xv;
                A0h[r * 8 + k] = hi;
                A0l[r * 8 + k] = (_Float16)(xv - (float)hi);
            }
        }
        BARRIER();                           // B3: h0(t) + x(t+1) visible

        // ---- layer 1 GEMM: stream pos 5..12 (h0 from A0, h1 from A1) ----
#pragma unroll
        for (int tt = 0; tt < 4; ++tt) {
            f32x4 b = {bv1[tt], bv1[tt], bv1[tt], bv1[tt]};
            acc[tt] = b;
        }
        LOADA(A0h, A0l, 1 + quad, 0)
        LOADA(A0h, A0l, 5 + quad, 1)    COMP(acc, 0, 2) LOADB(8, 2)
        LOADA(A0h, A0l, 9 + quad, 0)    COMP(acc, 1, 0) LOADB(9, 0)
        LOADA(A0h, A0l, 13 + quad, 1)   COMP(acc, 0, 1) LOADB(10, 1)
        LOADA(A1h_, A1l_, quad, 0)      COMP(acc, 1, 2) LOADB(11, 2)
        LOADA(A1h_, A1l_, 4 + quad, 1)  COMP(acc, 0, 0) LOADB(12, 0)
        LOADA(A1h_, A1l_, 8 + quad, 0)  COMP(acc, 1, 1) LOADB(1, 1)   // next t
        LOADA(A1h_, A1l_, 12 + quad, 1) COMP(acc, 0, 2) LOADB(2, 2)   // next t
                                        COMP(acc, 1, 0) LOADB(0, 0)   // next t
        BARRIER();                           // B4: all A1/A0 reads done

        // ---- cell 1 -> write h1 (A1 chunks 0..15) ----
#pragma unroll
        for (int r = 0; r < 4; ++r) {
            float ig = sigm(acc[0][r]);
            float fg = sigm(acc[1][r]);
            float gg = tanh_fast(acc[2][r]);
            float og = sigm(acc[3][r]);
            float cn = fg * c1[r] + ig * gg;
            c1[r] = cn;
            float h = og * tanh_fast(cn);
            _Float16 hi = (_Float16)h;
            int row = quad * 4 + r;
            int i1 = ((u >> 3) * ROWP + row) * 8 + (u & 7);
            A1h_[i1] = hi;
            A1l_[i1] = (_Float16)(h - (float)hi);
        }

        // ---- decode head (12 of 60 steps) ----
        if (t >= LOOKBACK) {
            BARRIER();                       // B5: h1(t) visible
            if (tid < TILE_B * 16) {         // 16 threads per batch row
                int r = tid >> 4, sub = tid & 15;
                float p = 0.0f;
#pragma unroll
                for (int i = 0; i < HIDDEN / 16; ++i) {
                    int uu = sub + i * 16;
                    int idx = ((uu >> 3) * ROWP + r) * 8 + (uu & 7);
                    p += ((float)A1h_[idx] + (float)A1l_[idx]) * wfcs[uu];
                }
#pragma unroll
                for (int off = 8; off; off >>= 1) p += __shfl_down(p, off, 16);
                if (sub == 0) {
                    float pr = p + bfc;
                    out[(size_t)(batch0 + r) * HORIZON + (t - LOOKBACK)] = pr;
                    if (t + 1 < TTOT) {      // BG feedback -> x(t+1) slot k=0
                        _Float16 hi = (_Float16)pr;
                        A0h[r * 8] = hi;
                        A0l[r * 8] = (_Float16)(pr - (float)hi);
                    }
                }
            }
            BARRIER();                       // B6: BG slot visible
        }
        // encoder: no extra barrier — next B2 orders cell1's A1 writes
    }
#undef WPOS
#undef LOADB
#undef LOADA
#undef COMP
}

extern "C" void kernel_launch(void* const* d_in, const int* in_sizes, int n_in,
                              void* d_out, int out_size, void* d_ws, size_t ws_size,
                              hipStream_t stream) {
    const float* input = (const float*)d_in[0];
    const float* Wih0  = (const float*)d_in[1];
    const float* Whh0  = (const float*)d_in[2];
    const float* bi0   = (const float*)d_in[3];
    const float* bh0   = (const float*)d_in[4];
    const float* Wih1  = (const float*)d_in[5];
    const float* Whh1  = (const float*)d_in[6];
    const float* bi1   = (const float*)d_in[7];
    const float* bh1   = (const float*)d_in[8];
    const float* W_fc  = (const float*)d_in[9];
    const float* b_fc  = (const float*)d_in[10];

    _Float16* wfrag = (_Float16*)d_ws;
    float* bias = (float*)((char*)d_ws + (size_t)W_HALFS * sizeof(_Float16));

    int total = W_HALFS + 2 * GATES;
    setup_kernel<<<(total + 255) / 256, 256, 0, stream>>>(
        Wih0, Whh0, bi0, bh0, Wih1, Whh1, bi1, bh1, wfrag, bias);

    lstm_kernel<<<BATCH / TILE_B, NTHREADS, 0, stream>>>(
        input, wfrag, bias, W_fc, b_fc, (float*)d_out);
}

// Round 9
// 411.344 us; speedup vs baseline: 1.7114x; 1.7114x over previous
//
#include <hip/hip_runtime.h>

#define LOOKBACK 48
#define HORIZON  12
#define TTOT     60
#define INPUT_DIM 8
#define HIDDEN   128
#define GATES    512
#define BATCH    8192
#define TILE_B   32          /* batch rows per block (2 M-tiles of 16) */
#define NTHREADS 512         /* 8 waves; wave s owns hidden units s*16..s*16+15 */
#define NSLICES  8
#define L0_KS    5           /* layer0 K = 160 (8 x + 128 h0 + 24 zero-pad) */
#define L1_KS    8           /* layer1 K = 256 (128 h0 + 128 h1) */
#define FRAGS_PER_KS 4       /* 4 gate-type N-tiles, single fp16 B */
#define FRAG_SHORTS 512      /* 1KB per fragment */
#define KSTRIDE  (FRAGS_PER_KS * FRAG_SHORTS)            /* 2048 halves per K-step */
#define SLICE_FRAGS ((L0_KS + L1_KS) * FRAGS_PER_KS)     /* 52 */
#define W_HALFS  (NSLICES * SLICE_FRAGS * FRAG_SHORTS)   /* 212992 halves = 416KB */

/* A-plane LDS (in-place state), SINGLE fp16 plane:
   A0: chunk0 = x (k=0..7), chunks 1..16 = h0 (chunk 1+(u>>3)), 17..19 zero pad.
   A1: chunks 0..15 = h1.
   chunk = [ROWP rows][8 fp16], ROWP=33 (32 rows + 1 pad row). */
#define ROWP 33
#define A0_CHUNKS 20
#define A1_CHUNKS 16
#define A0_HALFS (A0_CHUNKS * ROWP * 8)   /* 5280 */
#define A1_HALFS (A1_CHUNKS * ROWP * 8)   /* 4224 */

typedef __attribute__((ext_vector_type(8))) _Float16 half8;
typedef __attribute__((ext_vector_type(4))) float f32x4;

/* 1-instr hardware reciprocal (v_rcp_f32, ~1 ulp) — avoids the IEEE division
   expansion (~9 VALU ops each) that dominated the cell-update cost. */
__device__ __forceinline__ float frcp(float x) { return __builtin_amdgcn_rcpf(x); }

__device__ __forceinline__ float sigm(float x) {
    return frcp(1.0f + __expf(-x));
}
__device__ __forceinline__ float tanh_fast(float x) {
    float ax = fabsf(x);
    float e  = __expf(-2.0f * ax);
    float t  = (1.0f - e) * frcp(1.0f + e);
    return copysignf(t, x);
}

/* Barrier WITHOUT vmcnt drain: LDS ordering only; global conveyor loads stay
   in flight across the barrier. */
#define BARRIER() __asm__ volatile("s_waitcnt lgkmcnt(0)\ns_barrier" ::: "memory")

// ------------- setup: fp16 weights in MFMA-fragment order -------------
// frag element (lane, j) = W_l[k = ks*32 + (lane>>4)*8 + j][row = t*128 + s*16 + (lane&15)]
__global__ void setup_kernel(const float* __restrict__ Wih0, const float* __restrict__ Whh0,
                             const float* __restrict__ bi0,  const float* __restrict__ bh0,
                             const float* __restrict__ Wih1, const float* __restrict__ Whh1,
                             const float* __restrict__ bi1,  const float* __restrict__ bh1,
                             _Float16* __restrict__ wfrag, float* __restrict__ bias) {
    int idx = blockIdx.x * blockDim.x + threadIdx.x;
    if (idx < W_HALFS) {
        int e = idx & 511, frag = idx >> 9;
        int lane = e >> 3, j = e & 7;
        int t = frag & 3;
        int rest = frag >> 2;
        int lks = rest % (L0_KS + L1_KS), s = rest / (L0_KS + L1_KS);
        int l = (lks < L0_KS) ? 0 : 1;
        int ks = l ? (lks - L0_KS) : lks;
        int k = ks * 32 + ((lane >> 4) << 3) + j;
        int uu = s * 16 + (lane & 15);
        int row = t * HIDDEN + uu;
        float v = 0.0f;
        if (l == 0) {
            if (k < INPUT_DIM) v = Wih0[row * INPUT_DIM + k];
            else if (k < INPUT_DIM + HIDDEN) v = Whh0[row * HIDDEN + (k - INPUT_DIM)];
        } else {
            if (k < HIDDEN) v = Wih1[row * HIDDEN + k];
            else v = Whh1[row * HIDDEN + (k - HIDDEN)];
        }
        wfrag[idx] = (_Float16)v;
    } else if (idx < W_HALFS + 2 * GATES) {
        int g = idx - W_HALFS;
        bias[g] = (g < GATES) ? (bi0[g] + bh0[g]) : (bi1[g - GATES] + bh1[g - GATES]);
    }
}

// ------------- persistent 2-layer LSTM, single-fp16 MFMA + conveyor -------------
__global__ __launch_bounds__(NTHREADS, 2)
void lstm_kernel(const float* __restrict__ input,   // [B,60,8]
                 const _Float16* __restrict__ wfrag,
                 const float* __restrict__ bias01,  // [1024]
                 const float* __restrict__ W_fc,    // [128]
                 const float* __restrict__ b_fc,
                 float* __restrict__ out) {         // [B,12]
    __shared__ _Float16 A0[A0_HALFS];
    __shared__ _Float16 A1[A1_HALFS];
    __shared__ float wfcs[HIDDEN];

    const int tid  = threadIdx.x;
    const int lane = tid & 63;
    const int s    = tid >> 6;
    const int col  = lane & 15;
    const int quad = lane >> 4;
    const int u    = s * 16 + col;
    const int batch0 = blockIdx.x * TILE_B;

    const _Float16* w0 = wfrag + s * (SLICE_FRAGS * FRAG_SHORTS);
    const _Float16* w1 = w0 + L0_KS * KSTRIDE;

    for (int i = tid; i < A0_HALFS; i += NTHREADS) A0[i] = (_Float16)0.f;
    for (int i = tid; i < A1_HALFS; i += NTHREADS) A1[i] = (_Float16)0.f;
    if (tid < HIDDEN) wfcs[tid] = W_fc[tid];
    const float bfc = b_fc[0];

    float bv0[4], bv1[4];
#pragma unroll
    for (int tt = 0; tt < 4; ++tt) {
        bv0[tt] = bias01[tt * HIDDEN + u];
        bv1[tt] = bias01[GATES + tt * HIDDEN + u];
    }

    float c0[2][4] = {}, c1[2][4] = {};

    // x(0) prefetch + stage
    float xv = 0.0f;
    if (tid < TILE_B * INPUT_DIM)
        xv = input[(size_t)(batch0 + (tid >> 3)) * (TTOT * INPUT_DIM) + (tid & 7)];
    BARRIER();                               // zero-init visible
    if (tid < TILE_B * INPUT_DIM)
        A0[(tid >> 3) * 8 + (tid & 7)] = (_Float16)xv;

    half8 bq[3][4];                          // B conveyor (depth 3, 4 gate frags)
    half8 ah[2][2];                          // A double buffer x 2 M-tiles

#define WPOS(p) ((p) < L0_KS ? (w0 + (p) * KSTRIDE) : (w1 + ((p) - L0_KS) * KSTRIDE))
#define LOADB(p, sl) { const _Float16* wp_ = WPOS(p) + lane * 8;                \
    _Pragma("unroll") for (int tt = 0; tt < 4; ++tt)                            \
        bq[sl][tt] = *(const half8*)(wp_ + tt * FRAG_SHORTS); }
#define LOADA(H, chunk, buf) { int base_ = ((chunk) * ROWP + col) * 8;          \
    ah[buf][0] = *(const half8*)(H + base_);                                    \
    ah[buf][1] = *(const half8*)(H + base_ + 16 * 8); }
#define COMP(ACC, ab, sl)                                                       \
    _Pragma("unroll") for (int tt = 0; tt < 4; ++tt)                            \
    _Pragma("unroll") for (int mt = 0; mt < 2; ++mt)                            \
        ACC[mt][tt] = __builtin_amdgcn_mfma_f32_16x16x32_f16(                   \
            ah[ab][mt], bq[sl][tt], ACC[mt][tt], 0, 0, 0);

    LOADB(0, 0) LOADB(1, 1) LOADB(2, 2)      // prime conveyor
    BARRIER();                               // x(0) staged & visible

#pragma unroll 1
    for (int t = 0; t < TTOT; ++t) {
        // prefetch x(t+1) into registers (consumed after B2)
        if (tid < TILE_B * INPUT_DIM && t + 1 < TTOT)
            xv = input[(size_t)(batch0 + (tid >> 3)) * (TTOT * INPUT_DIM)
                       + (t + 1) * INPUT_DIM + (tid & 7)];

        // ---- layer 0 GEMM: stream pos 0..4 ----
        f32x4 acc[2][4];
#pragma unroll
        for (int tt = 0; tt < 4; ++tt) {
            f32x4 b = {bv0[tt], bv0[tt], bv0[tt], bv0[tt]};
            acc[0][tt] = b; acc[1][tt] = b;
        }
        LOADA(A0, quad, 0)
        LOADA(A0, 4 + quad, 1)  COMP(acc, 0, 0) LOADB(3, 0)
        LOADA(A0, 8 + quad, 0)  COMP(acc, 1, 1) LOADB(4, 1)
        LOADA(A0, 12 + quad, 1) COMP(acc, 0, 2) LOADB(5, 2)
        LOADA(A0, 16 + quad, 0) COMP(acc, 1, 0) LOADB(6, 0)
                                COMP(acc, 0, 1) LOADB(7, 1)
        BARRIER();                           // B2: all A0 reads done

        // ---- cell 0 -> write h0 (A0 chunks 1..16); stage x(t+1) chunk 0 ----
#pragma unroll
        for (int mt = 0; mt < 2; ++mt) {
#pragma unroll
            for (int r = 0; r < 4; ++r) {
                float ig = sigm(acc[mt][0][r]);
                float fg = sigm(acc[mt][1][r]);
                float gg = tanh_fast(acc[mt][2][r]);
                float og = sigm(acc[mt][3][r]);
                float cn = fg * c0[mt][r] + ig * gg;
                c0[mt][r] = cn;
                float h = og * tanh_fast(cn);
                int row = mt * 16 + quad * 4 + r;
                A0[((1 + (u >> 3)) * ROWP + row) * 8 + (u & 7)] = (_Float16)h;
            }
        }
        if (tid < TILE_B * INPUT_DIM && t + 1 < TTOT) {
            int r = tid >> 3, k = tid & 7;
            if (!(t + 1 > LOOKBACK && k == 0))   // BG slot filled by fc instead
                A0[r * 8 + k] = (_Float16)xv;
        }
        BARRIER();                           // B3: h0(t) + x(t+1) visible

        // ---- layer 1 GEMM: stream pos 5..12 (h0 from A0, h1 from A1) ----
#pragma unroll
        for (int tt = 0; tt < 4; ++tt) {
            f32x4 b = {bv1[tt], bv1[tt], bv1[tt], bv1[tt]};
            acc[0][tt] = b; acc[1][tt] = b;
        }
        LOADA(A0, 1 + quad, 0)
        LOADA(A0, 5 + quad, 1)   COMP(acc, 0, 2) LOADB(8, 2)
        LOADA(A0, 9 + quad, 0)   COMP(acc, 1, 0) LOADB(9, 0)
        LOADA(A0, 13 + quad, 1)  COMP(acc, 0, 1) LOADB(10, 1)
        LOADA(A1, quad, 0)       COMP(acc, 1, 2) LOADB(11, 2)
        LOADA(A1, 4 + quad, 1)   COMP(acc, 0, 0) LOADB(12, 0)
        LOADA(A1, 8 + quad, 0)   COMP(acc, 1, 1) LOADB(1, 1)   // next t
        LOADA(A1, 12 + quad, 1)  COMP(acc, 0, 2) LOADB(2, 2)   // next t
                                 COMP(acc, 1, 0) LOADB(0, 0)   // next t
        BARRIER();                           // B4: all A1/A0 reads done

        // ---- cell 1 -> write h1 (A1 chunks 0..15) ----
#pragma unroll
        for (int mt = 0; mt < 2; ++mt) {
#pragma unroll
            for (int r = 0; r < 4; ++r) {
                float ig = sigm(acc[mt][0][r]);
                float fg = sigm(acc[mt][1][r]);
                float gg = tanh_fast(acc[mt][2][r]);
                float og = sigm(acc[mt][3][r]);
                float cn = fg * c1[mt][r] + ig * gg;
                c1[mt][r] = cn;
                float h = og * tanh_fast(cn);
                int row = mt * 16 + quad * 4 + r;
                A1[((u >> 3) * ROWP + row) * 8 + (u & 7)] = (_Float16)h;
            }
        }

        // ---- decode head (12 of 60 steps) ----
        if (t >= LOOKBACK) {
            BARRIER();                       // B5: h1(t) visible
            int r = tid >> 4, sub = tid & 15;
            float p = 0.0f;
#pragma unroll
            for (int i = 0; i < HIDDEN / 16; ++i) {
                int uu = sub + i * 16;
                p += (float)A1[((uu >> 3) * ROWP + r) * 8 + (uu & 7)] * wfcs[uu];
            }
#pragma unroll
            for (int off = 8; off; off >>= 1) p += __shfl_down(p, off, 16);
            if (sub == 0) {
                float pr = p + bfc;
                out[(size_t)(batch0 + r) * HORIZON + (t - LOOKBACK)] = pr;
                if (t + 1 < TTOT)            // BG feedback -> x(t+1) slot k=0
                    A0[r * 8] = (_Float16)pr;
            }
            BARRIER();                       // B6: BG slot visible
        }
        // encoder: no extra barrier — next B2 orders cell1's A1 writes
    }
#undef WPOS
#undef LOADB
#undef LOADA
#undef COMP
}

extern "C" void kernel_launch(void* const* d_in, const int* in_sizes, int n_in,
                              void* d_out, int out_size, void* d_ws, size_t ws_size,
                              hipStream_t stream) {
    const float* input = (const float*)d_in[0];
    const float* Wih0  = (const float*)d_in[1];
    const float* Whh0  = (const float*)d_in[2];
    const float* bi0   = (const float*)d_in[3];
    const float* bh0   = (const float*)d_in[4];
    const float* Wih1  = (const float*)d_in[5];
    const float* Whh1  = (const float*)d_in[6];
    const float* bi1   = (const float*)d_in[7];
    const float* bh1   = (const float*)d_in[8];
    const float* W_fc  = (const float*)d_in[9];
    const float* b_fc  = (const float*)d_in[10];

    _Float16* wfrag = (_Float16*)d_ws;
    float* bias = (float*)((char*)d_ws + (size_t)W_HALFS * sizeof(_Float16));

    int total = W_HALFS + 2 * GATES;
    setup_kernel<<<(total + 255) / 256, 256, 0, stream>>>(
        Wih0, Whh0, bi0, bh0, Wih1, Whh1, bi1, bh1, wfrag, bias);

    lstm_kernel<<<BATCH / TILE_B, NTHREADS, 0, stream>>>(
        input, wfrag, bias, W_fc, b_fc, (float*)d_out);
}

// Round 10
// 374.546 us; speedup vs baseline: 1.8796x; 1.0982x over previous
//
#include <hip/hip_runtime.h>

#define LOOKBACK 48
#define HORIZON  12
#define TTOT     60
#define INPUT_DIM 8
#define HIDDEN   128
#define GATES    512
#define BATCH    8192
#define TILE_B   32          /* batch rows per block (2 M-tiles of 16) */
#define NTHREADS 512         /* 8 waves; wave s owns hidden units s*16..s*16+15 */
#define NSLICES  8
#define L0_KS    5           /* layer0 K = 160 (8 x + 128 h0 + 24 zero-pad) */
#define L1_KS    8           /* layer1 K = 256 (128 h0 + 128 h1) */
#define FRAGS_PER_KS 4       /* 4 gate-type N-tiles, single fp16 B */
#define FRAG_SHORTS 512      /* 1KB per fragment */
#define KSTRIDE  (FRAGS_PER_KS * FRAG_SHORTS)            /* 2048 halves per K-step */
#define SLICE_FRAGS ((L0_KS + L1_KS) * FRAGS_PER_KS)     /* 52 */
#define W_HALFS  (NSLICES * SLICE_FRAGS * FRAG_SHORTS)   /* 212992 halves = 416KB */

/* A-plane LDS, parity double-buffered (1 barrier/encoder step):
   A0[par]: chunk0 = x, chunks 1..16 = h0 (chunk 1+(u>>3)), 17..19 zero pad.
   A1[par]: chunks 0..15 = h1.
   chunk = [ROWP rows][8 fp16], ROWP=33 (32 rows + 1 pad row). */
#define ROWP 33
#define A0_CHUNKS 20
#define A1_CHUNKS 16
#define A0_BUF (A0_CHUNKS * ROWP * 8)      /* 5280 */
#define A1_BUF (A1_CHUNKS * ROWP * 8)      /* 4224 */
#define A0_HALFS (2 * A0_BUF)
#define A1_HALFS (2 * A1_BUF)

typedef __attribute__((ext_vector_type(8))) _Float16 half8;
typedef __attribute__((ext_vector_type(4))) float f32x4;

__device__ __forceinline__ float frcp(float x) { return __builtin_amdgcn_rcpf(x); }
__device__ __forceinline__ float sigm(float x) {
    return frcp(1.0f + __expf(-x));
}
__device__ __forceinline__ float tanh_fast(float x) {
    float ax = fabsf(x);
    float e  = __expf(-2.0f * ax);
    float t  = (1.0f - e) * frcp(1.0f + e);
    return copysignf(t, x);
}

/* Barrier WITHOUT vmcnt drain: LDS ordering only; global conveyor loads stay
   in flight across the barrier. */
#define BARRIER() __asm__ volatile("s_waitcnt lgkmcnt(0)\ns_barrier" ::: "memory")

// ------------- setup: fp16 weights in MFMA-fragment order -------------
__global__ void setup_kernel(const float* __restrict__ Wih0, const float* __restrict__ Whh0,
                             const float* __restrict__ bi0,  const float* __restrict__ bh0,
                             const float* __restrict__ Wih1, const float* __restrict__ Whh1,
                             const float* __restrict__ bi1,  const float* __restrict__ bh1,
                             _Float16* __restrict__ wfrag, float* __restrict__ bias) {
    int idx = blockIdx.x * blockDim.x + threadIdx.x;
    if (idx < W_HALFS) {
        int e = idx & 511, frag = idx >> 9;
        int lane = e >> 3, j = e & 7;
        int t = frag & 3;
        int rest = frag >> 2;
        int lks = rest % (L0_KS + L1_KS), s = rest / (L0_KS + L1_KS);
        int l = (lks < L0_KS) ? 0 : 1;
        int ks = l ? (lks - L0_KS) : lks;
        int k = ks * 32 + ((lane >> 4) << 3) + j;
        int uu = s * 16 + (lane & 15);
        int row = t * HIDDEN + uu;
        float v = 0.0f;
        if (l == 0) {
            if (k < INPUT_DIM) v = Wih0[row * INPUT_DIM + k];
            else if (k < INPUT_DIM + HIDDEN) v = Whh0[row * HIDDEN + (k - INPUT_DIM)];
        } else {
            if (k < HIDDEN) v = Wih1[row * HIDDEN + k];
            else v = Whh1[row * HIDDEN + (k - HIDDEN)];
        }
        wfrag[idx] = (_Float16)v;
    } else if (idx < W_HALFS + 2 * GATES) {
        int g = idx - W_HALFS;
        bias[g] = (g < GATES) ? (bi0[g] + bh0[g]) : (bi1[g - GATES] + bh1[g - GATES]);
    }
}

// ------------- persistent 2-layer LSTM, fp16 MFMA, 1-barrier encoder step -------------
__global__ __launch_bounds__(NTHREADS, 2)
void lstm_kernel(const float* __restrict__ input,   // [B,60,8]
                 const _Float16* __restrict__ wfrag,
                 const float* __restrict__ bias01,  // [1024]
                 const float* __restrict__ W_fc,    // [128]
                 const float* __restrict__ b_fc,
                 float* __restrict__ out) {         // [B,12]
    __shared__ _Float16 A0[A0_HALFS];
    __shared__ _Float16 A1[A1_HALFS];
    __shared__ float wfcs[HIDDEN];

    const int tid  = threadIdx.x;
    const int lane = tid & 63;
    const int s    = tid >> 6;
    const int col  = lane & 15;
    const int quad = lane >> 4;
    const int u    = s * 16 + col;
    const int batch0 = blockIdx.x * TILE_B;

    /* wave-uniform weight base -> SGPR addressing for the B conveyor */
    uintptr_t wp64 = (uintptr_t)(wfrag + s * (SLICE_FRAGS * FRAG_SHORTS));
    wp64 = ((uintptr_t)__builtin_amdgcn_readfirstlane((unsigned)(wp64 >> 32)) << 32)
         | __builtin_amdgcn_readfirstlane((unsigned)wp64);
    const _Float16* wbase = (const _Float16*)wp64;

    for (int i = tid; i < A0_HALFS; i += NTHREADS) A0[i] = (_Float16)0.f;
    for (int i = tid; i < A1_HALFS; i += NTHREADS) A1[i] = (_Float16)0.f;
    if (tid < HIDDEN) wfcs[tid] = W_fc[tid];
    const float bfc = b_fc[0];

    float bv0[4], bv1[4];
#pragma unroll
    for (int tt = 0; tt < 4; ++tt) {
        bv0[tt] = bias01[tt * HIDDEN + u];
        bv1[tt] = bias01[GATES + tt * HIDDEN + u];
    }

    float c0[2][4] = {}, c1[2][4] = {};

    // x(0) prefetch + stage into parity-0 buffer
    float xv = 0.0f;
    if (tid < TILE_B * INPUT_DIM)
        xv = input[(size_t)(batch0 + (tid >> 3)) * (TTOT * INPUT_DIM) + (tid & 7)];
    BARRIER();                               // zero-init visible
    if (tid < TILE_B * INPUT_DIM)
        A0[(tid >> 3) * 8 + (tid & 7)] = (_Float16)xv;

    half8 bq[3][4];                          // B conveyor (depth 3, 4 gate frags)
    half8 ah[2][2];                          // A double buffer x 2 M-tiles

#define LOADB(p, sl) {                                                          \
    _Pragma("unroll") for (int tt = 0; tt < 4; ++tt)                            \
        bq[sl][tt] = *(const half8*)(wbase + (p) * KSTRIDE                      \
                                     + tt * FRAG_SHORTS + lane * 8); }
#define LOADA(H, off, chunk, buf) { int base_ = (off) + ((chunk) * ROWP + col) * 8; \
    ah[buf][0] = *(const half8*)(H + base_);                                    \
    ah[buf][1] = *(const half8*)(H + base_ + 16 * 8); }
#define COMP(ACC, ab, sl)                                                       \
    _Pragma("unroll") for (int tt = 0; tt < 4; ++tt)                            \
    _Pragma("unroll") for (int mt = 0; mt < 2; ++mt)                            \
        ACC[mt][tt] = __builtin_amdgcn_mfma_f32_16x16x32_f16(                   \
            ah[ab][mt], bq[sl][tt], ACC[mt][tt], 0, 0, 0);

    LOADB(0, 0) LOADB(1, 1) LOADB(2, 2)      // prime conveyor
    BARRIER();                               // x(0) staged & visible

#pragma unroll 1
    for (int t = 0; t < TTOT; ++t) {
        const int rb = t & 1, wb = rb ^ 1;
        const int a0r = rb * A0_BUF, a0w = wb * A0_BUF;
        const int a1r = rb * A1_BUF, a1w = wb * A1_BUF;

        // prefetch x(t+1)
        if (tid < TILE_B * INPUT_DIM && t + 1 < TTOT)
            xv = input[(size_t)(batch0 + (tid >> 3)) * (TTOT * INPUT_DIM)
                       + (t + 1) * INPUT_DIM + (tid & 7)];

        // ======== P1: GEMM0 reads A0[rb] (x(t), h0(t-1)) ========
        f32x4 acc[2][4];
#pragma unroll
        for (int tt = 0; tt < 4; ++tt) {
            f32x4 b = {bv0[tt], bv0[tt], bv0[tt], bv0[tt]};
            acc[0][tt] = b; acc[1][tt] = b;
        }
        LOADA(A0, a0r, quad, 0)
        LOADA(A0, a0r, 4 + quad, 1)  COMP(acc, 0, 0) LOADB(3, 0)
        LOADA(A0, a0r, 8 + quad, 0)  COMP(acc, 1, 1) LOADB(4, 1)
        LOADA(A0, a0r, 12 + quad, 1) COMP(acc, 0, 2) LOADB(5, 2)
        LOADA(A0, a0r, 16 + quad, 0) COMP(acc, 1, 0) LOADB(6, 0)
                                     COMP(acc, 0, 1) LOADB(7, 1)

        // cell 0 -> h0(t) into A0[wb] chunks 1..16 (no barrier needed: parity)
#pragma unroll
        for (int mt = 0; mt < 2; ++mt) {
#pragma unroll
            for (int r = 0; r < 4; ++r) {
                float ig = sigm(acc[mt][0][r]);
                float fg = sigm(acc[mt][1][r]);
                float gg = tanh_fast(acc[mt][2][r]);
                float og = sigm(acc[mt][3][r]);
                float cn = fg * c0[mt][r] + ig * gg;
                c0[mt][r] = cn;
                float h = og * tanh_fast(cn);
                int row = mt * 16 + quad * 4 + r;
                A0[a0w + ((1 + (u >> 3)) * ROWP + row) * 8 + (u & 7)] = (_Float16)h;
            }
        }
        // stage x(t+1) into A0[wb] chunk 0 (BG slot filled by fc for decode)
        if (tid < TILE_B * INPUT_DIM && t + 1 < TTOT) {
            int r = tid >> 3, k = tid & 7;
            if (!(t + 1 > LOOKBACK && k == 0))
                A0[a0w + r * 8 + k] = (_Float16)xv;
        }
        BARRIER();                           // B3: h0(t) + x(t+1) visible (the ONLY encoder barrier)

        // ======== P2: GEMM1 reads h0(t) from A0[wb], h1(t-1) from A1[rb] ========
#pragma unroll
        for (int tt = 0; tt < 4; ++tt) {
            f32x4 b = {bv1[tt], bv1[tt], bv1[tt], bv1[tt]};
            acc[0][tt] = b; acc[1][tt] = b;
        }
        LOADA(A0, a0w, 1 + quad, 0)
        LOADA(A0, a0w, 5 + quad, 1)   COMP(acc, 0, 2) LOADB(8, 2)
        LOADA(A0, a0w, 9 + quad, 0)   COMP(acc, 1, 0) LOADB(9, 0)
        LOADA(A0, a0w, 13 + quad, 1)  COMP(acc, 0, 1) LOADB(10, 1)
        LOADA(A1, a1r, quad, 0)       COMP(acc, 1, 2) LOADB(11, 2)
        LOADA(A1, a1r, 4 + quad, 1)   COMP(acc, 0, 0) LOADB(12, 0)
        LOADA(A1, a1r, 8 + quad, 0)   COMP(acc, 1, 1) LOADB(1, 1)   // next t
        LOADA(A1, a1r, 12 + quad, 1)  COMP(acc, 0, 2) LOADB(2, 2)   // next t
                                      COMP(acc, 1, 0) LOADB(0, 0)   // next t

        // cell 1 -> h1(t) into A1[wb] (no barrier: parity; next B3 publishes)
#pragma unroll
        for (int mt = 0; mt < 2; ++mt) {
#pragma unroll
            for (int r = 0; r < 4; ++r) {
                float ig = sigm(acc[mt][0][r]);
                float fg = sigm(acc[mt][1][r]);
                float gg = tanh_fast(acc[mt][2][r]);
                float og = sigm(acc[mt][3][r]);
                float cn = fg * c1[mt][r] + ig * gg;
                c1[mt][r] = cn;
                float h = og * tanh_fast(cn);
                int row = mt * 16 + quad * 4 + r;
                A1[a1w + ((u >> 3) * ROWP + row) * 8 + (u & 7)] = (_Float16)h;
            }
        }

        // ======== decode head (12 of 60 steps) ========
        if (t >= LOOKBACK) {
            BARRIER();                       // B5: h1(t) visible
            int r = tid >> 4, sub = tid & 15;
            float p = 0.0f;
#pragma unroll
            for (int i = 0; i < HIDDEN / 16; ++i) {
                int uu = sub + i * 16;
                p += (float)A1[a1w + ((uu >> 3) * ROWP + r) * 8 + (uu & 7)] * wfcs[uu];
            }
#pragma unroll
            for (int off = 8; off; off >>= 1) p += __shfl_down(p, off, 16);
            if (sub == 0) {
                float pr = p + bfc;
                out[(size_t)(batch0 + r) * HORIZON + (t - LOOKBACK)] = pr;
                if (t + 1 < TTOT)            // BG feedback -> x(t+1) slot k=0 in A0[wb]
                    A0[a0w + r * 8] = (_Float16)pr;
            }
            BARRIER();                       // B6: BG slot visible
        }
    }
#undef LOADB
#undef LOADA
#undef COMP
}

extern "C" void kernel_launch(void* const* d_in, const int* in_sizes, int n_in,
                              void* d_out, int out_size, void* d_ws, size_t ws_size,
                              hipStream_t stream) {
    const float* input = (const float*)d_in[0];
    const float* Wih0  = (const float*)d_in[1];
    const float* Whh0  = (const float*)d_in[2];
    const float* bi0   = (const float*)d_in[3];
    const float* bh0   = (const float*)d_in[4];
    const float* Wih1  = (const float*)d_in[5];
    const float* Whh1  = (const float*)d_in[6];
    const float* bi1   = (const float*)d_in[7];
    const float* bh1   = (const float*)d_in[8];
    const float* W_fc  = (const float*)d_in[9];
    const float* b_fc  = (const float*)d_in[10];

    _Float16* wfrag = (_Float16*)d_ws;
    float* bias = (float*)((char*)d_ws + (size_t)W_HALFS * sizeof(_Float16));

    int total = W_HALFS + 2 * GATES;
    setup_kernel<<<(total + 255) / 256, 256, 0, stream>>>(
        Wih0, Whh0, bi0, bh0, Wih1, Whh1, bi1, bh1, wfrag, bias);

    lstm_kernel<<<BATCH / TILE_B, NTHREADS, 0, stream>>>(
        input, wfrag, bias, W_fc, b_fc, (float*)d_out);
}